// Round 4
// baseline (376.492 us; speedup 1.0000x reference)
//
#include <hip/hip_runtime.h>
#include <cstdint>
#include <math.h>

typedef unsigned short u16;
typedef __bf16 bf16x8 __attribute__((ext_vector_type(8)));
typedef float f32x4 __attribute__((ext_vector_type(4)));

constexpr int Bc = 2, Sc = 2048, Dc = 1024, Hc = 16, DHc = 64;

__device__ __forceinline__ u16 f2bf(float f) {
  uint32_t u = __builtin_bit_cast(uint32_t, f);
  u += 0x7fffu + ((u >> 16) & 1u);
  return (u16)(u >> 16);
}
__device__ __forceinline__ float bf2f(u16 h) {
  uint32_t u = ((uint32_t)h) << 16;
  return __builtin_bit_cast(float, u);
}
__device__ __forceinline__ f32x4 mfma16(bf16x8 a, bf16x8 b, f32x4 c) {
  return __builtin_amdgcn_mfma_f32_16x16x32_bf16(a, b, c, 0, 0, 0);
}

// ---------------- f32 -> bf16 conversion, 4 elems/thread ----------------
__global__ __launch_bounds__(256) void cvt_kernel(const float* __restrict__ in,
                                                  u16* __restrict__ out, int n4) {
  int i = blockIdx.x * 256 + threadIdx.x;
  if (i >= n4) return;
  float4 v = reinterpret_cast<const float4*>(in)[i];
  ushort4 o;
  o.x = f2bf(v.x); o.y = f2bf(v.y); o.z = f2bf(v.z); o.w = f2bf(v.w);
  reinterpret_cast<ushort4*>(out)[i] = o;
}

// ---------------- generic bf16 GEMM: C[m][n] = (sum_k A[m][k]*B[n][k] + bias[n]) * scale
__global__ __launch_bounds__(256) void gemm_bt(
    const u16* __restrict__ A, const u16* __restrict__ Bw,
    const float* __restrict__ bias, int M, int N, int K, float scale,
    u16* __restrict__ outb, float* __restrict__ outf,
    int DHn, long strideB, long strideS, long strideH, long strideE) {
  constexpr int LDK = 40;  // 32 + 8 pad -> conflict-free ds_read_b128
  __shared__ u16 As[128 * LDK];
  __shared__ u16 Bs[128 * LDK];
  const int tid = threadIdx.x;
  const int lane = tid & 63;
  const int w = tid >> 6, wm = w >> 1, wn = w & 1;
  const int lo = lane & 15, hi = lane >> 4;
  const int m0 = blockIdx.y * 128, n0 = blockIdx.x * 128;
  const f32x4 vzero = {0.f, 0.f, 0.f, 0.f};

  f32x4 acc[4][4];
  #pragma unroll
  for (int i = 0; i < 4; ++i)
    #pragma unroll
    for (int j = 0; j < 4; ++j) acc[i][j] = vzero;

  for (int k0 = 0; k0 < K; k0 += 32) {
    #pragma unroll
    for (int it = 0; it < 2; ++it) {
      const int e = (tid + it * 256) * 8;
      const int r = e >> 5, c = e & 31;
      *reinterpret_cast<uint4*>(&As[r * LDK + c]) =
          *reinterpret_cast<const uint4*>(&A[(long)(m0 + r) * K + k0 + c]);
      int nr = n0 + r; nr = nr < N ? nr : N - 1;  // clamp (vproj N=64)
      *reinterpret_cast<uint4*>(&Bs[r * LDK + c]) =
          *reinterpret_cast<const uint4*>(&Bw[(long)nr * K + k0 + c]);
    }
    __syncthreads();
    bf16x8 af[4], bfr[4];
    #pragma unroll
    for (int mi = 0; mi < 4; ++mi)
      af[mi] = *reinterpret_cast<const bf16x8*>(&As[(wm * 64 + mi * 16 + lo) * LDK + hi * 8]);
    #pragma unroll
    for (int nj = 0; nj < 4; ++nj)
      bfr[nj] = *reinterpret_cast<const bf16x8*>(&Bs[(wn * 64 + nj * 16 + lo) * LDK + hi * 8]);
    #pragma unroll
    for (int mi = 0; mi < 4; ++mi)
      #pragma unroll
      for (int nj = 0; nj < 4; ++nj)
        acc[mi][nj] = mfma16(af[mi], bfr[nj], acc[mi][nj]);
    __syncthreads();
  }

  #pragma unroll
  for (int nj = 0; nj < 4; ++nj) {
    const int n = n0 + wn * 64 + nj * 16 + lo;
    if (n >= N) continue;
    const float bb = bias ? bias[n] : 0.f;
    const int hh = n / DHn, ee = n % DHn;
    #pragma unroll
    for (int mi = 0; mi < 4; ++mi) {
      #pragma unroll
      for (int r = 0; r < 4; ++r) {
        const int mm = m0 + wm * 64 + mi * 16 + hi * 4 + r;
        const int bidx = mm >> 11, ss = mm & 2047;  // S = 2048
        const long idx = bidx * strideB + ss * strideS + hh * strideH + ee * strideE;
        const float val = (acc[mi][nj][r] + bb) * scale;
        if (outf) outf[idx] = val;
        else outb[idx] = f2bf(val);
      }
    }
  }
}

// ---------------- fused causal attention, z^T (swapped-operand) layout
// mfma(K,Q): lane (lo,hi) owns row s = s0+lo; per 64-col iter holds
// t = t0 + c*16 + hi*4 + r  (c=chunk, r=reg). Online softmax is lane-local.
// qh pre-scaled by log2(e)/8, so z is in log2 domain: p = exp2(z - off).
// qh,kh: [B,H,S,DH] bf16. vT: [B,DH,S] bf16. outh: [B,H,S,DH] bf16.
// attn_out: [B,S,H,S] f32.
__global__ __launch_bounds__(256, 4) void attn_fused(
    const u16* __restrict__ qh, const u16* __restrict__ kh,
    const u16* __restrict__ vT, u16* __restrict__ outh,
    float* __restrict__ attn_out) {
  __shared__ u16 plds[4 * 16 * 80];  // per-wave [16 rows][64+pad t] transpose buffer
  const int tid = threadIdx.x;
  const int lane = tid & 63, w = tid >> 6;
  const int lo = lane & 15, hi = lane >> 4;
  const int blk = blockIdx.x;
  const int jj = blk & 31, h = (blk >> 5) & 15, b = blk >> 9;  // 32*16*2 = 1024
  const long bh = (long)(b * Hc + h) * Sc;
  const long rowstride = (long)Hc * Sc;  // 32768
  float* aout = attn_out + (long)b * Sc * rowstride + (long)h * Sc;
  u16* pbuf = &plds[w * 16 * 80];
  const f32x4 vzero = {0.f, 0.f, 0.f, 0.f};

  // balanced strips per block: {2jj, 2jj+1, 126-2jj, 127-2jj} sum to 254 for all jj
  const int strip = (w < 2) ? (2 * jj + w) : ((w == 2) ? (126 - 2 * jj) : (127 - 2 * jj));
  const int s0 = strip * 16;
  const int srow = s0 + lo;                     // this lane's q-row
  const int send = ((s0 + 16 + 63) >> 6) << 6;  // live region end, 64-aligned

  bf16x8 qa0, qa1;
  {
    const u16* qp = &qh[(bh + s0 + lo) * DHc];
    qa0 = *reinterpret_cast<const bf16x8*>(&qp[hi * 8]);
    qa1 = *reinterpret_cast<const bf16x8*>(&qp[32 + hi * 8]);
  }

  // ---- pass 1: lane-local online max/sum ----
  float m = -1e30f, l = 0.f;
  #pragma unroll 1
  for (int t0 = 0; t0 < send; t0 += 64) {
    f32x4 z[4];
    #pragma unroll
    for (int c = 0; c < 4; ++c) {
      const u16* kp = &kh[(bh + t0 + c * 16 + lo) * DHc];
      bf16x8 kb0 = *reinterpret_cast<const bf16x8*>(&kp[hi * 8]);
      bf16x8 kb1 = *reinterpret_cast<const bf16x8*>(&kp[32 + hi * 8]);
      z[c] = mfma16(kb1, qa1, mfma16(kb0, qa0, vzero));
    }
    // raw max (inflated max over masked entries is harmless: p=exp2(z-m)/l exact)
    float mt = -1e30f;
    #pragma unroll
    for (int c = 0; c < 4; ++c)
      #pragma unroll
      for (int r = 0; r < 4; ++r) mt = fmaxf(mt, z[c][r]);
    const float mn = fmaxf(m, mt);
    float sum = 0.f;
    if (t0 + 63 <= s0) {  // fully live
      #pragma unroll
      for (int c = 0; c < 4; ++c)
        #pragma unroll
        for (int r = 0; r < 4; ++r) sum += exp2f(z[c][r] - mn);
    } else {  // diagonal-crossing: zero masked contributions after exp
      #pragma unroll
      for (int c = 0; c < 4; ++c)
        #pragma unroll
        for (int r = 0; r < 4; ++r) {
          const int t = t0 + c * 16 + hi * 4 + r;
          const float e = exp2f(z[c][r] - mn);
          sum += (t <= srow) ? e : 0.f;
        }
    }
    l = l * exp2f(m - mn) + sum;
    m = mn;
  }
  // combine the 4 hi-lane partials of each row (lanes lo, lo+16, lo+32, lo+48)
  #pragma unroll
  for (int dd = 16; dd < 64; dd <<= 1) {
    const float mo = __shfl_xor(m, dd);
    const float lx = __shfl_xor(l, dd);
    const float mn = fmaxf(m, mo);
    l = l * exp2f(m - mn) + lx * exp2f(mo - mn);
    m = mn;
  }
  const float off = m + log2f(l);  // p = exp2(z - off)

  // ---- pass 2: recompute, store p (float4), LDS-transpose, PV ----
  f32x4 acco[4];
  #pragma unroll
  for (int eb = 0; eb < 4; ++eb) acco[eb] = vzero;

  #pragma unroll 1
  for (int t0 = 0; t0 < send; t0 += 64) {
    bf16x8 kbs[4][2];
    #pragma unroll
    for (int c = 0; c < 4; ++c) {
      const u16* kp = &kh[(bh + t0 + c * 16 + lo) * DHc];
      kbs[c][0] = *reinterpret_cast<const bf16x8*>(&kp[hi * 8]);
      kbs[c][1] = *reinterpret_cast<const bf16x8*>(&kp[32 + hi * 8]);
    }
    const bool full = (t0 + 63 <= s0);
    #pragma unroll
    for (int c = 0; c < 4; ++c) {
      f32x4 z = mfma16(kbs[c][1], qa1, mfma16(kbs[c][0], qa0, vzero));
      float p[4];
      #pragma unroll
      for (int r = 0; r < 4; ++r) {
        const float e = exp2f(z[r] - off);
        p[r] = (full || (t0 + c * 16 + hi * 4 + r <= srow)) ? e : 0.f;
      }
      float4 v4 = {p[0], p[1], p[2], p[3]};
      *reinterpret_cast<float4*>(aout + (long)srow * rowstride + t0 + c * 16 + hi * 4) = v4;
      uint2 pk;
      pk.x = (uint32_t)f2bf(p[0]) | ((uint32_t)f2bf(p[1]) << 16);
      pk.y = (uint32_t)f2bf(p[2]) | ((uint32_t)f2bf(p[3]) << 16);
      *reinterpret_cast<uint2*>(&pbuf[lo * 80 + c * 16 + hi * 4]) = pk;
    }
    asm volatile("s_waitcnt lgkmcnt(0)" ::: "memory");
    __builtin_amdgcn_sched_barrier(0);
    bf16x8 pa0 = *reinterpret_cast<const bf16x8*>(&pbuf[lo * 80 + hi * 8]);
    bf16x8 pa1 = *reinterpret_cast<const bf16x8*>(&pbuf[lo * 80 + 32 + hi * 8]);
    const u16* vp = &vT[((long)b * DHc + lo) * Sc + t0 + hi * 8];
    #pragma unroll
    for (int eb = 0; eb < 4; ++eb) {
      bf16x8 vb0 = *reinterpret_cast<const bf16x8*>(&vp[(long)eb * 16 * Sc]);
      bf16x8 vb1 = *reinterpret_cast<const bf16x8*>(&vp[(long)eb * 16 * Sc + 32]);
      acco[eb] = mfma16(pa0, vb0, acco[eb]);
      acco[eb] = mfma16(pa1, vb1, acco[eb]);
    }
  }

  // ---- epilogue: outh store (D-layout rows s0+hi*4+r) + zero-fill masked region ----
  #pragma unroll
  for (int eb = 0; eb < 4; ++eb)
    #pragma unroll
    for (int r = 0; r < 4; ++r)
      outh[(bh + s0 + hi * 4 + r) * DHc + eb * 16 + lo] = f2bf(acco[eb][r]);

  const float4 z4 = {0.f, 0.f, 0.f, 0.f};
  float* frow = aout + (long)srow * rowstride;
  #pragma unroll 1
  for (int tf = send; tf < Sc; tf += 16)
    *reinterpret_cast<float4*>(frow + tf + hi * 4) = z4;
}

// ---------------- mean over heads
__global__ __launch_bounds__(256) void mean_kernel(const u16* __restrict__ outh,
                                                   u16* __restrict__ meanb) {
  const int idx = blockIdx.x * 256 + threadIdx.x;  // 32768 threads
  const int bs = idx >> 3;
  const int e0 = (idx & 7) * 8;
  const int b = bs >> 11, s = bs & 2047;
  float acc[8];
  #pragma unroll
  for (int j = 0; j < 8; ++j) acc[j] = 0.f;
  for (int h = 0; h < Hc; ++h) {
    alignas(16) u16 tmp[8];
    *reinterpret_cast<uint4*>(tmp) =
        *reinterpret_cast<const uint4*>(&outh[((long)(b * Hc + h) * Sc + s) * DHc + e0]);
    #pragma unroll
    for (int j = 0; j < 8; ++j) acc[j] += bf2f(tmp[j]);
  }
  alignas(16) u16 o[8];
  #pragma unroll
  for (int j = 0; j < 8; ++j) o[j] = f2bf(acc[j] * 0.0625f);
  *reinterpret_cast<uint4*>(&meanb[(long)bs * DHc + e0]) = *reinterpret_cast<const uint4*>(o);
}

extern "C" void kernel_launch(void* const* d_in, const int* in_sizes, int n_in,
                              void* d_out, int out_size, void* d_ws, size_t ws_size,
                              hipStream_t stream) {
  (void)in_sizes; (void)n_in; (void)out_size; (void)ws_size;
  const float* q  = (const float*)d_in[0];
  const float* k  = (const float*)d_in[1];
  const float* v  = (const float*)d_in[2];
  const float* Wv = (const float*)d_in[4];
  const float* bv = (const float*)d_in[5];
  const float* Wq = (const float*)d_in[6];
  const float* bq = (const float*)d_in[7];
  const float* Wk = (const float*)d_in[8];
  const float* bk = (const float*)d_in[9];
  const float* Wo = (const float*)d_in[10];

  char* ws = (char*)d_ws;
  u16* qbf   = (u16*)(ws + 0);          // 8.0 MB
  u16* kbf   = (u16*)(ws + 8388608);
  u16* vbf   = (u16*)(ws + 16777216);
  u16* Wqbf  = (u16*)(ws + 25165824);   // 2 MB
  u16* Wkbf  = (u16*)(ws + 27262976);
  u16* Wvbf  = (u16*)(ws + 29360128);   // 128 KB
  u16* Wobf  = (u16*)(ws + 29491200);
  u16* qhb   = (u16*)(ws + 29622272);   // 8 MB  [B,H,S,DH]
  u16* khb   = (u16*)(ws + 38010880);
  u16* vTb   = (u16*)(ws + 46399488);   // 512 KB [B,DH,S]
  u16* outh  = (u16*)(ws + 46923776);   // 8 MB  [B,H,S,DH]
  u16* meanb = (u16*)(ws + 55312384);   // 512 KB

  float* outp  = (float*)d_out;
  float* attnp = (float*)d_out + (long)Bc * Sc * Dc;

  auto cvt = [&](const float* in, u16* out, int n) {
    cvt_kernel<<<(n / 4 + 255) / 256, 256, 0, stream>>>(in, out, n / 4);
  };
  cvt(q,  qbf,  Bc * Sc * Dc);
  cvt(k,  kbf,  Bc * Sc * Dc);
  cvt(v,  vbf,  Bc * Sc * Dc);
  cvt(Wq, Wqbf, Hc * DHc * Dc);
  cvt(Wk, Wkbf, Hc * DHc * Dc);
  cvt(Wv, Wvbf, DHc * Dc);
  cvt(Wo, Wobf, Dc * DHc);

  const int M = Bc * Sc;  // 4096
  // qh scale folds 1/sqrt(DH) AND log2(e) (attn runs in exp2 domain)
  const float qscale = 0.125f * 1.4426950408889634f;
  gemm_bt<<<dim3(8, 32), 256, 0, stream>>>(qbf, Wqbf, bq, M, 1024, 1024, qscale,
      qhb, nullptr, 64, 2097152L, 64L, 131072L, 1L);
  gemm_bt<<<dim3(8, 32), 256, 0, stream>>>(kbf, Wkbf, bk, M, 1024, 1024, 1.0f,
      khb, nullptr, 64, 2097152L, 64L, 131072L, 1L);
  gemm_bt<<<dim3(1, 32), 256, 0, stream>>>(vbf, Wvbf, bv, M, 64, 1024, 1.0f,
      vTb, nullptr, 64, 131072L, 1L, 0L, 2048L);

  attn_fused<<<1024, 256, 0, stream>>>(qhb, khb, vTb, outh, attnp);

  mean_kernel<<<128, 256, 0, stream>>>(outh, meanb);

  gemm_bt<<<dim3(8, 32), 256, 0, stream>>>(meanb, Wobf, nullptr, M, 1024, 64, 1.0f,
      nullptr, outp, 1024, 2097152L, 1024L, 0L, 1L);
}